// Round 14
// baseline (184.534 us; speedup 1.0000x reference)
//
#include <hip/hip_runtime.h>
#include <math.h>

typedef short bf16x8 __attribute__((ext_vector_type(8)));   // 8 bf16 in 4 VGPRs
typedef float f32x4  __attribute__((ext_vector_type(4)));
typedef float f32x2  __attribute__((ext_vector_type(2)));   // -> v_pk_*_f32

#define TPB 256
#define GRID 1024         // persistent: 4 blocks/CU, 16 waves/CU
#define NW   (GRID * 4)   // 4096 waves; chunk stride between a wave's chunks
#define CROWS 32          // rows per chunk (2 MFMA tiles)
#define CSTRIDE 36        // Ct row stride (floats): rows 16B-aligned
#define BFR_BYTES 16384   // 2 ntiles x 4 ksteps x 2 planes x 64 lanes x 16B
#define CT_BYTES (4 * CROWS * CSTRIDE * 4)   // 18432; LDS total 34816 -> 4 blocks/CU
#define BOFF(nt, ks, p) ((((nt)*4 + (ks))*2 + (p))*256)

#define PKFMA(a, b, c) __builtin_elementwise_fma((a), (b), (c))

__device__ __forceinline__ unsigned cvt_pk_bf16(float lo, float hi) {
    unsigned r;
    asm("v_cvt_pk_bf16_f32 %0, %1, %2" : "=v"(r) : "v"(lo), "v"(hi));
    return r;
}
// 2-plane split of a pair: p = RNE(x0,x1); q = RNE(residuals)
__device__ __forceinline__ void split2pk(float x0, float x1, unsigned &p, unsigned &q) {
    p = cvt_pk_bf16(x0, x1);
    f32x2 xv = {x0, x1};
    f32x2 fv = {__uint_as_float(p << 16), __uint_as_float(p & 0xffff0000u)};
    f32x2 r = xv - fv;
    q = cvt_pk_bf16(r.x, r.y);
}
__device__ __forceinline__ f32x2 leaky2(f32x2 y) {
    const f32x2 zero = {0.f, 0.f};
    const f32x2 slope = {0.1f, 0.1f};
    return PKFMA(__builtin_elementwise_min(y, zero), slope,
                 __builtin_elementwise_max(y, zero));
}
__device__ __forceinline__ float leaky1(float y) {
    return fmaxf(y, 0.f) + 0.1f * fminf(y, 0.f);
}

// load one 16-row A-tile fragment slice for this lane
__device__ __forceinline__ void load_tile(float4 (&dst)[8], const float* __restrict__ feat,
                                          unsigned rbase, int arow, int acol, unsigned nm1) {
    unsigned rr = rbase + arow;
    rr = rr < nm1 ? rr : nm1;                    // v_min_u32
    const float* ap = feat + (size_t)rr * 128 + acol;
#pragma unroll
    for (int ks = 0; ks < 4; ++ks) {
        dst[2 * ks]     = *(const float4*)(ap + ks * 32);
        dst[2 * ks + 1] = *(const float4*)(ap + ks * 32 + 4);
    }
}

// cvt + 6 MFMA for one 16-row tile from a register slot
__device__ __forceinline__ void do_tile(const float4 (&S)[8], const unsigned* bfr, int l,
                                        f32x4 &acc0, f32x4 &acc1) {
#pragma unroll
    for (int ks = 0; ks < 4; ++ks) {
        float v[8];
        *(float4*)(v)     = S[2 * ks];
        *(float4*)(v + 4) = S[2 * ks + 1];
        unsigned p[4], q[4];
#pragma unroll
        for (int i = 0; i < 4; ++i) split2pk(v[2*i], v[2*i+1], p[i], q[i]);
        uint4 q1 = {p[0], p[1], p[2], p[3]};
        uint4 q2 = {q[0], q[1], q[2], q[3]};
        bf16x8 a1 = __builtin_bit_cast(bf16x8, q1);
        bf16x8 a2 = __builtin_bit_cast(bf16x8, q2);
        bf16x8 B10 = __builtin_bit_cast(bf16x8, *(const uint4*)(bfr + BOFF(0, ks, 0) + l * 4));
        bf16x8 B20 = __builtin_bit_cast(bf16x8, *(const uint4*)(bfr + BOFF(0, ks, 1) + l * 4));
        bf16x8 B11 = __builtin_bit_cast(bf16x8, *(const uint4*)(bfr + BOFF(1, ks, 0) + l * 4));
        bf16x8 B21 = __builtin_bit_cast(bf16x8, *(const uint4*)(bfr + BOFF(1, ks, 1) + l * 4));
        acc0 = __builtin_amdgcn_mfma_f32_16x16x32_bf16(a1, B10, acc0, 0, 0, 0);
        acc1 = __builtin_amdgcn_mfma_f32_16x16x32_bf16(a1, B11, acc1, 0, 0, 0);
        acc0 = __builtin_amdgcn_mfma_f32_16x16x32_bf16(a2, B10, acc0, 0, 0, 0);
        acc1 = __builtin_amdgcn_mfma_f32_16x16x32_bf16(a2, B11, acc1, 0, 0, 0);
        acc0 = __builtin_amdgcn_mfma_f32_16x16x32_bf16(a1, B20, acc0, 0, 0, 0);
        acc1 = __builtin_amdgcn_mfma_f32_16x16x32_bf16(a1, B21, acc1, 0, 0, 0);
    }
}

__device__ __forceinline__ void ct_write(float* myCt, int j, int l,
                                         const f32x4 &a0, const f32x4 &a1) {
    const int crow = j * 16 + ((l >> 4) << 2);   // C/D: col=l&15, row=(l>>4)*4+r
    const int ccol = l & 15;
#pragma unroll
    for (int r = 0; r < 4; ++r) {
        myCt[(crow + r) * CSTRIDE + ccol]      = a0[r];
        myCt[(crow + r) * CSTRIDE + 16 + ccol] = a1[r];
    }
}

__global__ __launch_bounds__(TPB, 4) void decoder_kernel(
    const float* __restrict__ feat,
    const float* __restrict__ W1, const float* __restrict__ g1, const float* __restrict__ b1,
    const float* __restrict__ W2, const float* __restrict__ g2, const float* __restrict__ b2,
    const float* __restrict__ W3, const float* __restrict__ b3,
    float* __restrict__ out, int N, unsigned nchunks)
{
    __shared__ __align__(16) unsigned char lds[BFR_BYTES + CT_BYTES];  // 34816 B -> 4/CU
    unsigned* bfr = (unsigned*)lds;

    const int t = threadIdx.x;
    const int l = t & 63;
    const int w = t >> 6;
    const int arow = l & 15;        // A-fragment: m = l&15
    const int acol = (l >> 4) * 8;  //             k-base = (l>>4)*8
    const unsigned nm1 = (unsigned)(N - 1);
    float* myCt = (float*)(lds + BFR_BYTES) + w * CROWS * CSTRIDE;  // wave-private

    const unsigned wid = blockIdx.x * 4 + w;   // global wave id

    float4 s0[8], s1[8];                       // two register slots (64 VGPR)
    unsigned c = wid;
    if (c < nchunks) {                          // preload both tiles of first chunk
        load_tile(s0, feat, c * CROWS, arow, acol, nm1);
        load_tile(s1, feat, c * CROWS + 16, arow, acol, nm1);
    }

    // ---------------- prologue (once): W1 -> 2-plane bf16 B-fragments --------
    for (int cc = t; cc < 512; cc += 256) {
        const int lc = cc & 63, ks = (cc >> 6) & 3, nt = (cc >> 8) & 1;
        const float* wp = W1 + (nt * 16 + (lc & 15)) * 128 + ks * 32 + (lc >> 4) * 8;
        float v[8];
        *(float4*)(v)     = *(const float4*)(wp);
        *(float4*)(v + 4) = *(const float4*)(wp + 4);
        unsigned p[4], q[4];
#pragma unroll
        for (int i = 0; i < 4; ++i) split2pk(v[2*i], v[2*i+1], p[i], q[i]);
        uint4 q1 = {p[0], p[1], p[2], p[3]};
        uint4 q2 = {q[0], q[1], q[2], q[3]};
        *(uint4*)(bfr + BOFF(nt, ks, 0) + lc * 4) = q1;
        *(uint4*)(bfr + BOFF(nt, ks, 1) + lc * 4) = q2;
    }
    __syncthreads();   // the ONLY barrier; bfr read-only hereafter, waves free-run

    // ---------------- persistent per-wave chunk loop --------------------------
    for (; c < nchunks; c += NW) {
        const unsigned base = c * CROWS;
        const unsigned cn = c + NW;
        const bool hn = (cn < nchunks);

        {   // tile 0: consume s0 (issued one full chunk ago), then refill s0
            f32x4 a0 = {0,0,0,0}, a1 = {0,0,0,0};
            do_tile(s0, bfr, l, a0, a1);
            ct_write(myCt, 0, l, a0, a1);
            if (hn) load_tile(s0, feat, cn * CROWS, arow, acol, nm1);
        }
        {   // tile 1: consume s1, refill s1; both next-tiles fly through the tail
            f32x4 a0 = {0,0,0,0}, a1 = {0,0,0,0};
            do_tile(s1, bfr, l, a0, a1);
            ct_write(myCt, 1, l, a0, a1);
            if (hn) load_tile(s1, feat, cn * CROWS + 16, arow, acol, nm1);
        }

        // in-wave handoff (DS in-order per wave, wave-private Ct): no barrier.
        // Lanes r and r+32 both process row r (pair-read is an LDS broadcast).
        const int r = l & 31;
        const float* myrowp = myCt + r * CSTRIDE;

        // ---- pass A: streaming stats (no resident x array) -------------------
        f32x2 sv = {0.f, 0.f}, qv = {0.f, 0.f};
#pragma unroll
        for (int cc = 0; cc < 8; ++cc) {
            const float4 v = *(const float4*)(myrowp + cc * 4);
            const f32x2 p0 = {v.x, v.y}, p1 = {v.z, v.w};
            sv += p0; sv += p1;
            qv = PKFMA(p0, p0, qv);
            qv = PKFMA(p1, p1, qv);
        }
        const float m   = (sv.x + sv.y) * (1.f / 32.f);
        const float ex2 = (qv.x + qv.y) * (1.f / 32.f);
        const float rs1 = rsqrtf(fmaxf(ex2 - m * m, 0.f) + 1e-5f);
        const f32x2 mv   = {m, m};
        const f32x2 rs1v = {rs1, rs1};

        // ---- pass B: layer 2 in two column-halves (z recomputed, not stored) -
        float a2[16];
#pragma unroll
        for (int k = 0; k < 16; ++k) a2[k] = 0.f;
#pragma unroll
        for (int h = 0; h < 2; ++h) {
            f32x2 zh[8];
#pragma unroll
            for (int cc = 0; cc < 4; ++cc) {
                const float4 v = *(const float4*)(myrowp + h * 16 + cc * 4);
                const int i0 = 2 * cc;
                const f32x2 p0 = {v.x, v.y}, p1 = {v.z, v.w};
                const f32x2 g0 = *(const f32x2*)(g1 + h * 16 + 2 * i0);
                const f32x2 g1b = *(const f32x2*)(g1 + h * 16 + 2 * i0 + 2);
                const f32x2 b0 = *(const f32x2*)(b1 + h * 16 + 2 * i0);
                const f32x2 b1b = *(const f32x2*)(b1 + h * 16 + 2 * i0 + 2);
                zh[i0]     = leaky2(PKFMA((p0 - mv) * rs1v, g0, b0));
                zh[i0 + 1] = leaky2(PKFMA((p1 - mv) * rs1v, g1b, b1b));
            }
#pragma unroll
            for (int k = 0; k < 16; ++k) {
                const float* __restrict__ wrow = W2 + k * 32 + h * 16;
                f32x2 acc = {0.f, 0.f};
#pragma unroll
                for (int i = 0; i < 8; ++i)
                    acc = PKFMA(zh[i], *(const f32x2*)(wrow + 2 * i), acc);
                a2[k] += acc.x + acc.y;
            }
        }

        // ---- LN2 + leaky + layer 3 + normalize (scalar, in place) ------------
        float m2 = 0.f, e2 = 0.f;
#pragma unroll
        for (int k = 0; k < 16; ++k) { m2 += a2[k]; e2 = fmaf(a2[k], a2[k], e2); }
        m2 *= (1.f / 16.f);
        const float rs2 = rsqrtf(fmaxf(e2 * (1.f / 16.f) - m2 * m2, 0.f) + 1e-5f);
#pragma unroll
        for (int k = 0; k < 16; ++k)
            a2[k] = leaky1((a2[k] - m2) * rs2 * g2[k] + b2[k]);   // z2 in place

        float o[3];
#pragma unroll
        for (int q = 0; q < 3; ++q) {
            const float* __restrict__ wrow = W3 + q * 16;
            float s = b3[q];
#pragma unroll
            for (int k = 0; k < 16; ++k) s = fmaf(a2[k], wrow[k], s);
            o[q] = s;
        }
        const float nrm = sqrtf(o[0]*o[0] + o[1]*o[1] + o[2]*o[2]);
        const float inv = 1.f / fmaxf(nrm, 1e-12f);

        const size_t myrow = (size_t)base + r;
        if (l < 32 && myrow < (size_t)N) {
            out[myrow * 3 + 0] = o[0] * inv;
            out[myrow * 3 + 1] = o[1] * inv;
            out[myrow * 3 + 2] = o[2] * inv;
        }
    }
}

extern "C" void kernel_launch(void* const* d_in, const int* in_sizes, int n_in,
                              void* d_out, int out_size, void* d_ws, size_t ws_size,
                              hipStream_t stream) {
    const float* feat = (const float*)d_in[0];
    const float* W1   = (const float*)d_in[1];
    const float* g1   = (const float*)d_in[2];
    const float* b1   = (const float*)d_in[3];
    const float* W2   = (const float*)d_in[4];
    const float* g2   = (const float*)d_in[5];
    const float* b2   = (const float*)d_in[6];
    const float* W3   = (const float*)d_in[7];
    const float* b3   = (const float*)d_in[8];
    float* out = (float*)d_out;

    const int N = in_sizes[0] / 128;
    const unsigned nchunks = (unsigned)((N + CROWS - 1) / CROWS);

    decoder_kernel<<<GRID, TPB, 0, stream>>>(feat, W1, g1, b1, W2, g2, b2, W3, b3,
                                             out, N, nchunks);
}

// Round 15
// 112.459 us; speedup vs baseline: 1.6409x; 1.6409x over previous
//
#include <hip/hip_runtime.h>
#include <math.h>

typedef short bf16x8 __attribute__((ext_vector_type(8)));   // 8 bf16 in 4 VGPRs
typedef float f32x4  __attribute__((ext_vector_type(4)));
typedef float f32x2  __attribute__((ext_vector_type(2)));   // -> v_pk_*_f32

#define TPB 256
#define GRID 768          // persistent: 3 blocks/CU (LDS-bound), 12 waves/CU
#define NWAVES (GRID * 4) // 3072 waves; balanced consecutive chunk partition
#define CROWS 64          // rows per chunk (4 MFMA tiles), as round 11
#define CSTRIDE 36        // Ct row stride (floats): rows 16B-aligned
#define BFR_BYTES 16384   // 2 ntiles x 4 ksteps x 2 planes x 64 lanes x 16B
#define CT_BYTES (256 * CSTRIDE * 4)
#define BOFF(nt, ks, p) ((((nt)*4 + (ks))*2 + (p))*256)

#define PKFMA(a, b, c) __builtin_elementwise_fma((a), (b), (c))

__device__ __forceinline__ unsigned cvt_pk_bf16(float lo, float hi) {
    unsigned r;
    asm("v_cvt_pk_bf16_f32 %0, %1, %2" : "=v"(r) : "v"(lo), "v"(hi));
    return r;
}
// 2-plane split of a pair: p = RNE(x0,x1); q = RNE(residuals)
__device__ __forceinline__ void split2pk(float x0, float x1, unsigned &p, unsigned &q) {
    p = cvt_pk_bf16(x0, x1);
    f32x2 xv = {x0, x1};
    f32x2 fv = {__uint_as_float(p << 16), __uint_as_float(p & 0xffff0000u)};
    f32x2 r = xv - fv;
    q = cvt_pk_bf16(r.x, r.y);
}
__device__ __forceinline__ f32x2 leaky2(f32x2 y) {
    const f32x2 zero = {0.f, 0.f};
    const f32x2 slope = {0.1f, 0.1f};
    return PKFMA(__builtin_elementwise_min(y, zero), slope,
                 __builtin_elementwise_max(y, zero));
}

// load one 16-row A-tile fragment slice for this lane
__device__ __forceinline__ void load_tile(float4 (&dst)[8], const float* __restrict__ feat,
                                          unsigned rbase, int arow, int acol, unsigned nm1) {
    unsigned rr = rbase + arow;
    rr = rr < nm1 ? rr : nm1;                    // v_min_u32
    const float* ap = feat + (size_t)rr * 128 + acol;
#pragma unroll
    for (int ks = 0; ks < 4; ++ks) {
        dst[2 * ks]     = *(const float4*)(ap + ks * 32);
        dst[2 * ks + 1] = *(const float4*)(ap + ks * 32 + 4);
    }
}

// cvt + 6 MFMA for one 16-row tile from a register slot
__device__ __forceinline__ void do_tile(const float4 (&S)[8], const unsigned* bfr, int l,
                                        f32x4 &acc0, f32x4 &acc1) {
#pragma unroll
    for (int ks = 0; ks < 4; ++ks) {
        float v[8];
        *(float4*)(v)     = S[2 * ks];
        *(float4*)(v + 4) = S[2 * ks + 1];
        unsigned p[4], q[4];
#pragma unroll
        for (int i = 0; i < 4; ++i) split2pk(v[2*i], v[2*i+1], p[i], q[i]);
        uint4 q1 = {p[0], p[1], p[2], p[3]};
        uint4 q2 = {q[0], q[1], q[2], q[3]};
        bf16x8 a1 = __builtin_bit_cast(bf16x8, q1);
        bf16x8 a2 = __builtin_bit_cast(bf16x8, q2);
        bf16x8 B10 = __builtin_bit_cast(bf16x8, *(const uint4*)(bfr + BOFF(0, ks, 0) + l * 4));
        bf16x8 B20 = __builtin_bit_cast(bf16x8, *(const uint4*)(bfr + BOFF(0, ks, 1) + l * 4));
        bf16x8 B11 = __builtin_bit_cast(bf16x8, *(const uint4*)(bfr + BOFF(1, ks, 0) + l * 4));
        bf16x8 B21 = __builtin_bit_cast(bf16x8, *(const uint4*)(bfr + BOFF(1, ks, 1) + l * 4));
        acc0 = __builtin_amdgcn_mfma_f32_16x16x32_bf16(a1, B10, acc0, 0, 0, 0);
        acc1 = __builtin_amdgcn_mfma_f32_16x16x32_bf16(a1, B11, acc1, 0, 0, 0);
        acc0 = __builtin_amdgcn_mfma_f32_16x16x32_bf16(a2, B10, acc0, 0, 0, 0);
        acc1 = __builtin_amdgcn_mfma_f32_16x16x32_bf16(a2, B11, acc1, 0, 0, 0);
        acc0 = __builtin_amdgcn_mfma_f32_16x16x32_bf16(a1, B20, acc0, 0, 0, 0);
        acc1 = __builtin_amdgcn_mfma_f32_16x16x32_bf16(a1, B21, acc1, 0, 0, 0);
    }
}

__device__ __forceinline__ void ct_write(float* myCt, int j, int l,
                                         const f32x4 &a0, const f32x4 &a1) {
    const int crow = j * 16 + ((l >> 4) << 2);   // C/D: col=l&15, row=(l>>4)*4+r
    const int ccol = l & 15;
#pragma unroll
    for (int r = 0; r < 4; ++r) {
        myCt[(crow + r) * CSTRIDE + ccol]      = a0[r];
        myCt[(crow + r) * CSTRIDE + 16 + ccol] = a1[r];
    }
}

__device__ __forceinline__ void tail_store(
    const float* myCt, int l, unsigned base,
    const float* __restrict__ g1, const float* __restrict__ b1,
    const float* __restrict__ W2, const float* __restrict__ g2, const float* __restrict__ b2,
    const float* __restrict__ W3, const float* __restrict__ b3,
    float* __restrict__ out, int N)
{
    f32x2 xp[16];
#pragma unroll
    for (int cc = 0; cc < 8; ++cc) {
        const float4 v = *(const float4*)(myCt + l * CSTRIDE + cc * 4);
        xp[2 * cc]     = f32x2{v.x, v.y};
        xp[2 * cc + 1] = f32x2{v.z, v.w};
    }

    f32x2 sv = xp[0];
#pragma unroll
    for (int i = 1; i < 16; ++i) sv += xp[i];
    const float m = (sv.x + sv.y) * (1.f / 32.f);
    const f32x2 mv = {m, m};
    f32x2 vv = {0.f, 0.f};
#pragma unroll
    for (int i = 0; i < 16; ++i) { const f32x2 d = xp[i] - mv; vv = PKFMA(d, d, vv); }
    const float rs1 = rsqrtf((vv.x + vv.y) * (1.f / 32.f) + 1e-5f);
    const f32x2 rs1v = {rs1, rs1};

#pragma unroll
    for (int i = 0; i < 16; ++i) {   // z in place over xp (register discipline)
        const f32x2 gb = *(const f32x2*)(g1 + 2 * i);
        const f32x2 bb = *(const f32x2*)(b1 + 2 * i);
        xp[i] = leaky2(PKFMA((xp[i] - mv) * rs1v, gb, bb));
    }

    float a2v[16];
#pragma unroll
    for (int k = 0; k < 16; ++k) {
        const float* __restrict__ wrow = W2 + k * 32;
        f32x2 acc = {0.f, 0.f};
#pragma unroll
        for (int jj = 0; jj < 16; ++jj)
            acc = PKFMA(xp[jj], *(const f32x2*)(wrow + 2 * jj), acc);
        a2v[k] = acc.x + acc.y;
    }

    f32x2 a2p[8];
#pragma unroll
    for (int i = 0; i < 8; ++i) a2p[i] = f32x2{a2v[2 * i], a2v[2 * i + 1]};

    f32x2 s2 = a2p[0];
#pragma unroll
    for (int i = 1; i < 8; ++i) s2 += a2p[i];
    const float m2 = (s2.x + s2.y) * (1.f / 16.f);
    const f32x2 m2v = {m2, m2};
    f32x2 v2v = {0.f, 0.f};
#pragma unroll
    for (int i = 0; i < 8; ++i) { const f32x2 d = a2p[i] - m2v; v2v = PKFMA(d, d, v2v); }
    const float rs2 = rsqrtf((v2v.x + v2v.y) * (1.f / 16.f) + 1e-5f);
    const f32x2 rs2v = {rs2, rs2};

#pragma unroll
    for (int i = 0; i < 8; ++i) {    // z2 in place
        const f32x2 gb = *(const f32x2*)(g2 + 2 * i);
        const f32x2 bb = *(const f32x2*)(b2 + 2 * i);
        a2p[i] = leaky2(PKFMA((a2p[i] - m2v) * rs2v, gb, bb));
    }

    float o[3];
#pragma unroll
    for (int q = 0; q < 3; ++q) {
        const float* __restrict__ wrow = W3 + q * 16;
        f32x2 acc = {0.f, 0.f};
#pragma unroll
        for (int jj = 0; jj < 8; ++jj)
            acc = PKFMA(a2p[jj], *(const f32x2*)(wrow + 2 * jj), acc);
        o[q] = b3[q] + acc.x + acc.y;
    }
    const float nrm = sqrtf(o[0]*o[0] + o[1]*o[1] + o[2]*o[2]);
    const float inv = 1.f / fmaxf(nrm, 1e-12f);

    const size_t myrow = (size_t)base + l;
    if (myrow < (size_t)N) {
        out[myrow * 3 + 0] = o[0] * inv;
        out[myrow * 3 + 1] = o[1] * inv;
        out[myrow * 3 + 2] = o[2] * inv;
    }
}

__global__ __launch_bounds__(TPB, 3) void decoder_kernel(
    const float* __restrict__ feat,
    const float* __restrict__ W1, const float* __restrict__ g1, const float* __restrict__ b1,
    const float* __restrict__ W2, const float* __restrict__ g2, const float* __restrict__ b2,
    const float* __restrict__ W3, const float* __restrict__ b3,
    float* __restrict__ out, int N, unsigned qq, unsigned rr_)
{
    __shared__ __align__(16) unsigned char lds[BFR_BYTES + CT_BYTES];  // 53248 B -> 3/CU
    unsigned* bfr = (unsigned*)lds;

    const int t = threadIdx.x;
    const int l = t & 63;
    const int w = t >> 6;
    const int arow = l & 15;        // A-fragment: m = l&15
    const int acol = (l >> 4) * 8;  //             k-base = (l>>4)*8
    const unsigned nm1 = (unsigned)(N - 1);
    float* myCt = (float*)(lds + BFR_BYTES) + w * 64 * CSTRIDE;  // wave-private slice

    // balanced consecutive partition: wave wid owns [my_start, my_end)
    const unsigned wid = blockIdx.x * 4 + w;
    const unsigned my_start = wid * qq + (wid < rr_ ? wid : rr_);
    const unsigned my_end   = my_start + qq + (wid < rr_ ? 1u : 0u);

    float4 s0[8], s1[8];            // two slots, depth-2 schedule (64 VGPR)
    if (my_start < my_end) {        // preload t0,t1 of first chunk; fly under prologue
        load_tile(s0, feat, my_start * CROWS, arow, acol, nm1);
        load_tile(s1, feat, my_start * CROWS + 16, arow, acol, nm1);
    }

    // ---------------- prologue (once): W1 -> 2-plane bf16 B-fragments --------
    for (int cc = t; cc < 512; cc += 256) {
        const int lc = cc & 63, ks = (cc >> 6) & 3, nt = (cc >> 8) & 1;
        const float* wp = W1 + (nt * 16 + (lc & 15)) * 128 + ks * 32 + (lc >> 4) * 8;
        float v[8];
        *(float4*)(v)     = *(const float4*)(wp);
        *(float4*)(v + 4) = *(const float4*)(wp + 4);
        unsigned p[4], q[4];
#pragma unroll
        for (int i = 0; i < 4; ++i) split2pk(v[2*i], v[2*i+1], p[i], q[i]);
        uint4 q1 = {p[0], p[1], p[2], p[3]};
        uint4 q2 = {q[0], q[1], q[2], q[3]};
        *(uint4*)(bfr + BOFF(nt, ks, 0) + lc * 4) = q1;
        *(uint4*)(bfr + BOFF(nt, ks, 1) + lc * 4) = q2;
    }
    __syncthreads();   // the ONLY barrier; bfr read-only hereafter, waves free-run

    // ---------------- persistent chunk loop (consecutive chunks) -------------
    for (unsigned c = my_start; c < my_end; ++c) {
        const unsigned base = c * CROWS;
        const bool hn = (c + 1 < my_end);

        {   // j=0: consume s0 (t0), refill s0 <- t2 (distance 2)
            f32x4 a0 = {0,0,0,0}, a1 = {0,0,0,0};
            do_tile(s0, bfr, l, a0, a1);
            ct_write(myCt, 0, l, a0, a1);
            load_tile(s0, feat, base + 32, arow, acol, nm1);
        }
        {   // j=1: consume s1 (t1), refill s1 <- t3
            f32x4 a0 = {0,0,0,0}, a1 = {0,0,0,0};
            do_tile(s1, bfr, l, a0, a1);
            ct_write(myCt, 1, l, a0, a1);
            load_tile(s1, feat, base + 48, arow, acol, nm1);
        }
        {   // j=2: consume s0 (t2), refill s0 <- next chunk t0
            f32x4 a0 = {0,0,0,0}, a1 = {0,0,0,0};
            do_tile(s0, bfr, l, a0, a1);
            ct_write(myCt, 2, l, a0, a1);
            if (hn) load_tile(s0, feat, (c + 1) * CROWS, arow, acol, nm1);
        }
        {   // j=3: consume s1 (t3), refill s1 <- next chunk t1
            f32x4 a0 = {0,0,0,0}, a1 = {0,0,0,0};
            do_tile(s1, bfr, l, a0, a1);
            ct_write(myCt, 3, l, a0, a1);
            if (hn) load_tile(s1, feat, (c + 1) * CROWS + 16, arow, acol, nm1);
        }

        // in-wave handoff (DS in-order per wave, wave-private Ct): no barrier.
        // Next chunk's t0+t1 (16 KB) stay in flight through the whole tail.
        tail_store(myCt, l, base, g1, b1, W2, g2, b2, W3, b3, out, N);
    }
}

extern "C" void kernel_launch(void* const* d_in, const int* in_sizes, int n_in,
                              void* d_out, int out_size, void* d_ws, size_t ws_size,
                              hipStream_t stream) {
    const float* feat = (const float*)d_in[0];
    const float* W1   = (const float*)d_in[1];
    const float* g1   = (const float*)d_in[2];
    const float* b1   = (const float*)d_in[3];
    const float* W2   = (const float*)d_in[4];
    const float* g2   = (const float*)d_in[5];
    const float* b2   = (const float*)d_in[6];
    const float* W3   = (const float*)d_in[7];
    const float* b3   = (const float*)d_in[8];
    float* out = (float*)d_out;

    const int N = in_sizes[0] / 128;
    const unsigned nchunks = (unsigned)((N + CROWS - 1) / CROWS);
    const unsigned q = nchunks / NWAVES;
    const unsigned r = nchunks % NWAVES;

    decoder_kernel<<<GRID, TPB, 0, stream>>>(feat, W1, g1, b1, W2, g2, b2, W3, b3,
                                             out, N, q, r);
}